// Round 5
// baseline (553.947 us; speedup 1.0000x reference)
//
#include <hip/hip_runtime.h>
#include <math.h>

#define N_ROWS 8192
#define NIN    256
#define NOUT   128
#define CUTOFF 45.0f
#define TOPK   32
#define NBINS  256
#define RANGE  384.0f
#define MAXL   256     // fast path handles |L| <= 256 (4 register passes/wave)

// block-wide (256-thread) max reduction; red is 4-float LDS scratch
__device__ __forceinline__ float block_max_256(float v, float* red) {
#pragma unroll
    for (int off = 32; off > 0; off >>= 1)
        v = fmaxf(v, __shfl_down(v, off, 64));
    if ((threadIdx.x & 63) == 0) red[threadIdx.x >> 6] = v;
    __syncthreads();
    float r = fmaxf(fmaxf(red[0], red[1]), fmaxf(red[2], red[3]));
    __syncthreads();
    return r;
}

// ---------------------------------------------------------------------------
// K1: s[i] = dot(h[i], w @ v2).  Grid = 1024 blocks, 8 rows/block (2/wave).
// ---------------------------------------------------------------------------
__global__ __launch_bounds__(256) void k_sw(const float* __restrict__ h,
                                            const float* __restrict__ w,
                                            const float* __restrict__ v,
                                            float* __restrict__ s) {
    __shared__ float wv[NIN];
    int tid = threadIdx.x;
    const float* wr = w + (size_t)tid * NOUT;
    const float* v2 = v + NOUT;
    float acc = 0.f;
#pragma unroll
    for (int n = 0; n < NOUT; n += 4) {
        float4 a = *(const float4*)(wr + n);
        float4 b = *(const float4*)(v2 + n);
        acc = fmaf(a.x, b.x, acc);
        acc = fmaf(a.y, b.y, acc);
        acc = fmaf(a.z, b.z, acc);
        acc = fmaf(a.w, b.w, acc);
    }
    wv[tid] = acc;
    __syncthreads();

    int wid  = tid >> 6;
    int lane = tid & 63;
    float4 wv4 = *(const float4*)(wv + lane * 4);
    int row0 = blockIdx.x * 8 + wid * 2;
#pragma unroll
    for (int r = 0; r < 2; ++r) {
        const float* hr = h + (size_t)(row0 + r) * NIN;
        float4 hv = *(const float4*)(hr + lane * 4);
        float a = hv.x * wv4.x;
        a = fmaf(hv.y, wv4.y, a);
        a = fmaf(hv.z, wv4.z, a);
        a = fmaf(hv.w, wv4.w, a);
#pragma unroll
        for (int off = 32; off > 0; off >>= 1)
            a += __shfl_down(a, off, 64);
        if (lane == 0) s[row0 + r] = a;
    }
}

// ---------------------------------------------------------------------------
// K23: FUSED histogram-threshold candidate selection + hwL2 compute.
//   Single block.  Candidate list kept in LDS for the hwL2 phase (no global
//   round-trip).  hwL2 stored COLUMN-INTERLEAVED: slot ((k&63)<<1)|(k>>6)
//   so k_att7's lane reads cols {lane, lane+64} as one float2.
//   Rows [nL, round8(nL)) zero-filled.  Also zeroes the uncertified counter.
// ---------------------------------------------------------------------------
__global__ __launch_bounds__(256) void k_topw(const float* __restrict__ s_g,
                                              const float* __restrict__ h,
                                              const float* __restrict__ w,
                                              int* __restrict__ L,
                                              float* __restrict__ Ls,
                                              int* __restrict__ nL_p,
                                              float* __restrict__ T_p,
                                              float* __restrict__ hwL2,
                                              int* __restrict__ nU_p) {
    __shared__ float sd[N_ROWS];   // 32 KiB
    __shared__ float red[4];
    __shared__ int   hist[NBINS];
    __shared__ int   c;
    __shared__ float Tsh;
    __shared__ int   Lsh[MAXL];
    int tid = threadIdx.x;
    hist[tid] = 0;
    float mloc = -INFINITY;
    for (int j = tid; j < N_ROWS; j += 256) {
        float v = s_g[j];
        sd[j] = v;
        mloc = fmaxf(mloc, v);
    }
    __syncthreads();
    float mstar = block_max_256(mloc, red);
    const float invw = (float)NBINS / RANGE;
    for (int j = tid; j < N_ROWS; j += 256) {
        int b = (int)((mstar - sd[j]) * invw);
        b = b < 0 ? 0 : (b > NBINS - 1 ? NBINS - 1 : b);
        atomicAdd(&hist[b], 1);
    }
    __syncthreads();
    if (tid == 0) {
        int cum = 0, B = NBINS - 1;
        for (int b = 0; b < NBINS; ++b) {
            cum += hist[b];
            if (cum >= TOPK) { B = b; break; }
        }
        Tsh = mstar - (float)(B + 1) * (RANGE / (float)NBINS) - CUTOFF;
        *T_p = Tsh;
        c = 0;
        *nU_p = 0;
    }
    __syncthreads();
    float T = Tsh;
    for (int j = tid; j < N_ROWS; j += 256) {
        float v = sd[j];
        if (v >= T) {
            int p = atomicAdd(&c, 1);
            L[p]  = j;
            Ls[p] = v;
            if (p < MAXL) Lsh[p] = j;
        }
    }
    __syncthreads();
    int nL = c;
    if (tid == 0) *nL_p = nL;
    if (nL > MAXL) return;          // fast path unused; k_att7 defers all rows

    // ---- hwL2 phase: 2 row-slots x 128 cols across 256 threads ----
    int nLp  = (nL + 7) & ~7;
    int k    = tid & 127;
    int sidx = ((k & 63) << 1) | (k >> 6);
    for (int t = tid >> 7; t < nLp; t += 2) {
        float acc = 0.f;
        if (t < nL) {
            const float* hr = h + (size_t)Lsh[t] * NIN;
#pragma unroll 4
            for (int n = 0; n < NIN; n += 4) {
                float4 hv = *(const float4*)(hr + n);
                acc = fmaf(hv.x, w[(size_t)(n + 0) * NOUT + k], acc);
                acc = fmaf(hv.y, w[(size_t)(n + 1) * NOUT + k], acc);
                acc = fmaf(hv.z, w[(size_t)(n + 2) * NOUT + k], acc);
                acc = fmaf(hv.w, w[(size_t)(n + 3) * NOUT + k], acc);
            }
        }
        hwL2[(size_t)t * NOUT + sidx] = acc;
    }
}

// ---------------------------------------------------------------------------
// K7: wave-per-row sparse attention, FAST PATH ONLY.
//   __launch_bounds__(256, 8) -> VGPR<=64 -> 32 waves/CU for the
//   gather-latency-bound phase (the fat exact-fallback lives in k_fix now).
//   Uncertified rows (never, in practice) append to UL for k_fix.
// ---------------------------------------------------------------------------
__global__ __launch_bounds__(256, 8) void k_att7(const int* __restrict__ adj,
                                                 const float* __restrict__ hwL2,
                                                 const int* __restrict__ L,
                                                 const float* __restrict__ Ls,
                                                 const int* __restrict__ nL_p,
                                                 const float* __restrict__ T_p,
                                                 float* __restrict__ out,
                                                 int* __restrict__ UL,
                                                 int* __restrict__ nU_p) {
    int wid  = threadIdx.x >> 6;
    int lane = threadIdx.x & 63;
    int i    = blockIdx.x * 4 + wid;
    int   nL = nL_p[0];
    float T  = T_p[0];
    const int* arow = adj + (size_t)i * N_ROWS;

    bool fast = (nL <= MAXL);
    float sv[4] = {-INFINITY, -INFINITY, -INFINITY, -INFINITY};
    float m = -INFINITY;

    if (fast) {
#pragma unroll
        for (int p = 0; p < 4; ++p) {
            int t = p * 64 + lane;
            if (t < nL) {
                int j = L[t];
                sv[p] = (arow[j] > 0) ? Ls[t] : -INFINITY;
            }
        }
        float mm = fmaxf(fmaxf(sv[0], sv[1]), fmaxf(sv[2], sv[3]));
#pragma unroll
        for (int off = 32; off > 0; off >>= 1)
            mm = fmaxf(mm, __shfl_down(mm, off, 64));
        m = __shfl(mm, 0, 64);
    }

    if (fast && (m - CUTOFF >= T)) {
        // parallel weights + denominator (out of the serial chain)
        float pw[4];
        float dp = 0.f;
#pragma unroll
        for (int p = 0; p < 4; ++p) {
            pw[p] = __expf(sv[p] - m);   // exp(-inf)=0 for non-neighbors/pad
            dp += pw[p];
        }
#pragma unroll
        for (int off = 32; off > 0; off >>= 1)
            dp += __shfl_down(dp, off, 64);
        float den = __shfl(dp, 0, 64);

        // survivor loop: numerator terms with non-negligible weight
        float th = m - CUTOFF;
        float acc0 = 0.f, acc1 = 0.f;
#pragma unroll
        for (int p = 0; p < 4; ++p) {
            unsigned long long bm = __ballot(sv[p] >= th);
            while (bm) {
                int t0 = __ffsll((long long)bm) - 1;
                bm &= bm - 1;
                float pwt = __shfl(pw[p], t0, 64);
                const float* g = hwL2 + (size_t)(p * 64 + t0) * NOUT + (lane << 1);
                float2 gv = *(const float2*)g;
                acc0 = fmaf(pwt, gv.x, acc0);
                acc1 = fmaf(pwt, gv.y, acc1);
            }
        }
        out[(size_t)i * NOUT + lane]      = acc0 / den;
        out[(size_t)i * NOUT + 64 + lane] = acc1 / den;
        return;
    }

    if (lane == 0) {
        int p = atomicAdd(nU_p, 1);
        UL[p] = i;
    }
}

// ---------------------------------------------------------------------------
// KFIX: exact fallback for uncertified rows (list UL, count nU).  In
//   practice nU == 0 and every block exits after one scalar load.
// ---------------------------------------------------------------------------
__global__ __launch_bounds__(256) void k_fix(const int* __restrict__ adj,
                                             const float* __restrict__ s_g,
                                             const float* __restrict__ h,
                                             const float* __restrict__ w,
                                             const int* __restrict__ UL,
                                             const int* __restrict__ nU_p,
                                             float* __restrict__ out) {
    int nU = nU_p[0];
    if (nU == 0) return;
    int wid  = threadIdx.x >> 6;
    int lane = threadIdx.x & 63;
    for (int u = blockIdx.x * 4 + wid; u < nU; u += gridDim.x * 4) {
        int i = UL[u];
        const int* arow = adj + (size_t)i * N_ROWS;
        float m2 = -INFINITY;
        for (int j0 = lane * 4; j0 < N_ROWS; j0 += 256) {
            int4   a  = *(const int4*)(arow + j0);
            float4 sx = *(const float4*)(s_g + j0);
            if (a.x > 0) m2 = fmaxf(m2, sx.x);
            if (a.y > 0) m2 = fmaxf(m2, sx.y);
            if (a.z > 0) m2 = fmaxf(m2, sx.z);
            if (a.w > 0) m2 = fmaxf(m2, sx.w);
        }
#pragma unroll
        for (int off = 32; off > 0; off >>= 1)
            m2 = fmaxf(m2, __shfl_down(m2, off, 64));
        m2 = __shfl(m2, 0, 64);

        if (m2 > -INFINITY) {
            // streaming exact accumulate; p underflows to 0 like reference
            float acc0 = 0.f, acc1 = 0.f, den = 0.f;
            for (int j = 0; j < N_ROWS; ++j) {
                if (arow[j] > 0) {
                    float p = __expf(s_g[j] - m2);
                    if (p > 0.f) {
                        den += p;
                        const float* hr = h + (size_t)j * NIN;
                        float d0 = 0.f, d1 = 0.f;
                        for (int nn = 0; nn < NIN; ++nn) {
                            float hv = hr[nn];
                            d0 = fmaf(hv, w[(size_t)nn * NOUT + lane], d0);
                            d1 = fmaf(hv, w[(size_t)nn * NOUT + 64 + lane], d1);
                        }
                        acc0 = fmaf(p, d0, acc0);
                        acc1 = fmaf(p, d1, acc1);
                    }
                }
            }
            out[(size_t)i * NOUT + lane]      = acc0 / den;
            out[(size_t)i * NOUT + 64 + lane] = acc1 / den;
        } else {
            // fully-masked row: uniform softmax -> colsum(h) @ w / N
            float cs[4] = {0.f, 0.f, 0.f, 0.f};
            for (int r = 0; r < N_ROWS; ++r) {
                const float* hr = h + (size_t)r * NIN;
#pragma unroll
                for (int q = 0; q < 4; ++q)
                    cs[q] += hr[lane + q * 64];
            }
            float acc0 = 0.f, acc1 = 0.f;
            for (int nn = 0; nn < NIN; ++nn) {
                float csv = __shfl(cs[nn >> 6], nn & 63, 64);
                acc0 = fmaf(csv, w[(size_t)nn * NOUT + lane], acc0);
                acc1 = fmaf(csv, w[(size_t)nn * NOUT + 64 + lane], acc1);
            }
            out[(size_t)i * NOUT + lane]      = acc0 / (float)N_ROWS;
            out[(size_t)i * NOUT + 64 + lane] = acc1 / (float)N_ROWS;
        }
    }
}

// ---------------------------------------------------------------------------
extern "C" void kernel_launch(void* const* d_in, const int* in_sizes, int n_in,
                              void* d_out, int out_size, void* d_ws, size_t ws_size,
                              hipStream_t stream) {
    const float* h   = (const float*)d_in[0];   // [8192, 256]
    const int*   adj = (const int*)  d_in[1];   // [8192, 8192]
    const float* w   = (const float*)d_in[2];   // [256, 128]
    const float* v   = (const float*)d_in[3];   // [256, 1]
    float* out = (float*)d_out;                 // [8192, 128]

    // workspace layout (bytes)
    char* ws = (char*)d_ws;
    float* hwL = (float*)(ws);                                  // 128 KiB
    size_t o   = (size_t)MAXL * NOUT * 4;
    float* s   = (float*)(ws + o);  o += (size_t)N_ROWS * 4;    // 32 KiB
    int*   L   = (int*)  (ws + o);  o += (size_t)N_ROWS * 4;    // 32 KiB
    float* Ls  = (float*)(ws + o);  o += (size_t)N_ROWS * 4;    // 32 KiB
    int*   UL  = (int*)  (ws + o);  o += (size_t)N_ROWS * 4;    // 32 KiB
    int*   nL  = (int*)  (ws + o);  o += 16;
    float* T   = (float*)(ws + o);  o += 16;
    int*   nU  = (int*)  (ws + o);

    k_sw  <<<N_ROWS / 8, 256, 0, stream>>>(h, w, v, s);
    k_topw<<<1,          256, 0, stream>>>(s, h, w, L, Ls, nL, T, hwL, nU);
    k_att7<<<N_ROWS / 4, 256, 0, stream>>>(adj, hwL, L, Ls, nL, T, out, UL, nU);
    k_fix <<<2048,       256, 0, stream>>>(adj, s, h, w, UL, nU, out);
}

// Round 6
// 375.123 us; speedup vs baseline: 1.4767x; 1.4767x over previous
//
#include <hip/hip_runtime.h>
#include <math.h>

#define N_ROWS 8192
#define NIN    256
#define NOUT   128
#define CUTOFF 45.0f
#define TOPK   32
#define NBINS  256
#define RANGE  384.0f
#define MAXL   256     // fast path handles |L| <= 256 (4 register passes/wave)

// block-wide (256-thread) max reduction; red is 4-float LDS scratch
__device__ __forceinline__ float block_max_256(float v, float* red) {
#pragma unroll
    for (int off = 32; off > 0; off >>= 1)
        v = fmaxf(v, __shfl_down(v, off, 64));
    if ((threadIdx.x & 63) == 0) red[threadIdx.x >> 6] = v;
    __syncthreads();
    float r = fmaxf(fmaxf(red[0], red[1]), fmaxf(red[2], red[3]));
    __syncthreads();
    return r;
}

// ---------------------------------------------------------------------------
// K1: s[i] = dot(h[i], w @ v2).  Grid = 1024 blocks, 8 rows/block (2/wave).
// ---------------------------------------------------------------------------
__global__ __launch_bounds__(256) void k_sw(const float* __restrict__ h,
                                            const float* __restrict__ w,
                                            const float* __restrict__ v,
                                            float* __restrict__ s) {
    __shared__ float wv[NIN];
    int tid = threadIdx.x;
    const float* wr = w + (size_t)tid * NOUT;
    const float* v2 = v + NOUT;
    float acc = 0.f;
#pragma unroll
    for (int n = 0; n < NOUT; n += 4) {
        float4 a = *(const float4*)(wr + n);
        float4 b = *(const float4*)(v2 + n);
        acc = fmaf(a.x, b.x, acc);
        acc = fmaf(a.y, b.y, acc);
        acc = fmaf(a.z, b.z, acc);
        acc = fmaf(a.w, b.w, acc);
    }
    wv[tid] = acc;
    __syncthreads();

    int wid  = tid >> 6;
    int lane = tid & 63;
    float4 wv4 = *(const float4*)(wv + lane * 4);
    int row0 = blockIdx.x * 8 + wid * 2;
#pragma unroll
    for (int r = 0; r < 2; ++r) {
        const float* hr = h + (size_t)(row0 + r) * NIN;
        float4 hv = *(const float4*)(hr + lane * 4);
        float a = hv.x * wv4.x;
        a = fmaf(hv.y, wv4.y, a);
        a = fmaf(hv.z, wv4.z, a);
        a = fmaf(hv.w, wv4.w, a);
#pragma unroll
        for (int off = 32; off > 0; off >>= 1)
            a += __shfl_down(a, off, 64);
        if (lane == 0) s[row0 + r] = a;
    }
}

// ---------------------------------------------------------------------------
// K2: histogram threshold + candidate list (single block, single pass).
//   Tiny kernel; also zeroes the uncertified-row counter for k_fix.
// ---------------------------------------------------------------------------
__global__ __launch_bounds__(256) void k_top(const float* __restrict__ s_g,
                                             int* __restrict__ L,
                                             float* __restrict__ Ls,
                                             int* __restrict__ nL_p,
                                             float* __restrict__ T_p,
                                             int* __restrict__ nU_p) {
    __shared__ float sd[N_ROWS];   // 32 KiB
    __shared__ float red[4];
    __shared__ int   hist[NBINS];
    __shared__ int   c;
    __shared__ float Tsh;
    int tid = threadIdx.x;
    hist[tid] = 0;
    float mloc = -INFINITY;
    for (int j = tid; j < N_ROWS; j += 256) {
        float v = s_g[j];
        sd[j] = v;
        mloc = fmaxf(mloc, v);
    }
    __syncthreads();
    float mstar = block_max_256(mloc, red);
    const float invw = (float)NBINS / RANGE;
    for (int j = tid; j < N_ROWS; j += 256) {
        int b = (int)((mstar - sd[j]) * invw);
        b = b < 0 ? 0 : (b > NBINS - 1 ? NBINS - 1 : b);
        atomicAdd(&hist[b], 1);
    }
    __syncthreads();
    if (tid == 0) {
        int cum = 0, B = NBINS - 1;
        for (int b = 0; b < NBINS; ++b) {
            cum += hist[b];
            if (cum >= TOPK) { B = b; break; }
        }
        Tsh = mstar - (float)(B + 1) * (RANGE / (float)NBINS) - CUTOFF;
        *T_p = Tsh;
        c = 0;
        *nU_p = 0;
    }
    __syncthreads();
    float T = Tsh;
    for (int j = tid; j < N_ROWS; j += 256) {
        float v = sd[j];
        if (v >= T) {
            int p = atomicAdd(&c, 1);
            L[p]  = j;
            Ls[p] = v;
        }
    }
    __syncthreads();
    if (tid == 0) *nL_p = c;
}

// ---------------------------------------------------------------------------
// K3: hwL2[t][:] = h[L[t]] @ w, 128 blocks (latency hidden across CUs).
//     Stored COLUMN-INTERLEAVED: slot ((k&63)<<1)|(k>>6) so k_att7's lane
//     reads cols {lane, lane+64} as one float2.  Rows [nL, round8(nL))
//     zero-filled (padded reads never see poison).
// ---------------------------------------------------------------------------
__global__ __launch_bounds__(128) void k_hwL(const float* __restrict__ h,
                                             const float* __restrict__ w,
                                             const int* __restrict__ L,
                                             const int* __restrict__ nL_p,
                                             float* __restrict__ hwL2) {
    int nL = *nL_p;
    if (nL > MAXL) return;          // fast path unused -> skip
    int nLp = (nL + 7) & ~7;
    int k = threadIdx.x;
    int sidx = ((k & 63) << 1) | (k >> 6);
    for (int t = blockIdx.x; t < nLp; t += gridDim.x) {
        float acc = 0.f;
        if (t < nL) {
            const float* hr = h + (size_t)L[t] * NIN;
#pragma unroll 4
            for (int n = 0; n < NIN; n += 4) {
                float4 hv = *(const float4*)(hr + n);
                acc = fmaf(hv.x, w[(size_t)(n + 0) * NOUT + k], acc);
                acc = fmaf(hv.y, w[(size_t)(n + 1) * NOUT + k], acc);
                acc = fmaf(hv.z, w[(size_t)(n + 2) * NOUT + k], acc);
                acc = fmaf(hv.w, w[(size_t)(n + 3) * NOUT + k], acc);
            }
        }
        hwL2[(size_t)t * NOUT + sidx] = acc;
    }
}

// ---------------------------------------------------------------------------
// K7: wave-per-row sparse attention, FAST PATH ONLY.
//   __launch_bounds__(256, 8) -> lean VGPR -> 32 waves/CU for the
//   gather-latency-bound phase (the fat exact-fallback lives in k_fix).
//   Uncertified rows (never, in practice) append to UL for k_fix.
// ---------------------------------------------------------------------------
__global__ __launch_bounds__(256, 8) void k_att7(const int* __restrict__ adj,
                                                 const float* __restrict__ hwL2,
                                                 const int* __restrict__ L,
                                                 const float* __restrict__ Ls,
                                                 const int* __restrict__ nL_p,
                                                 const float* __restrict__ T_p,
                                                 float* __restrict__ out,
                                                 int* __restrict__ UL,
                                                 int* __restrict__ nU_p) {
    int wid  = threadIdx.x >> 6;
    int lane = threadIdx.x & 63;
    int i    = blockIdx.x * 4 + wid;
    int   nL = nL_p[0];
    float T  = T_p[0];
    const int* arow = adj + (size_t)i * N_ROWS;

    bool fast = (nL <= MAXL);
    float sv[4] = {-INFINITY, -INFINITY, -INFINITY, -INFINITY};
    float m = -INFINITY;

    if (fast) {
#pragma unroll
        for (int p = 0; p < 4; ++p) {
            int t = p * 64 + lane;
            if (t < nL) {
                int j = L[t];
                sv[p] = (arow[j] > 0) ? Ls[t] : -INFINITY;
            }
        }
        float mm = fmaxf(fmaxf(sv[0], sv[1]), fmaxf(sv[2], sv[3]));
#pragma unroll
        for (int off = 32; off > 0; off >>= 1)
            mm = fmaxf(mm, __shfl_down(mm, off, 64));
        m = __shfl(mm, 0, 64);
    }

    if (fast && (m - CUTOFF >= T)) {
        // parallel weights + denominator (out of the serial chain)
        float pw[4];
        float dp = 0.f;
#pragma unroll
        for (int p = 0; p < 4; ++p) {
            pw[p] = __expf(sv[p] - m);   // exp(-inf)=0 for non-neighbors/pad
            dp += pw[p];
        }
#pragma unroll
        for (int off = 32; off > 0; off >>= 1)
            dp += __shfl_down(dp, off, 64);
        float den = __shfl(dp, 0, 64);

        // survivor loop: numerator terms with non-negligible weight
        float th = m - CUTOFF;
        float acc0 = 0.f, acc1 = 0.f;
#pragma unroll
        for (int p = 0; p < 4; ++p) {
            unsigned long long bm = __ballot(sv[p] >= th);
            while (bm) {
                int t0 = __ffsll((long long)bm) - 1;
                bm &= bm - 1;
                float pwt = __shfl(pw[p], t0, 64);
                const float* g = hwL2 + (size_t)(p * 64 + t0) * NOUT + (lane << 1);
                float2 gv = *(const float2*)g;
                acc0 = fmaf(pwt, gv.x, acc0);
                acc1 = fmaf(pwt, gv.y, acc1);
            }
        }
        out[(size_t)i * NOUT + lane]      = acc0 / den;
        out[(size_t)i * NOUT + 64 + lane] = acc1 / den;
        return;
    }

    if (lane == 0) {
        int p = atomicAdd(nU_p, 1);
        UL[p] = i;
    }
}

// ---------------------------------------------------------------------------
// KFIX: exact fallback for uncertified rows (list UL, count nU).  In
//   practice nU == 0 and every block exits after one scalar load.
// ---------------------------------------------------------------------------
__global__ __launch_bounds__(256) void k_fix(const int* __restrict__ adj,
                                             const float* __restrict__ s_g,
                                             const float* __restrict__ h,
                                             const float* __restrict__ w,
                                             const int* __restrict__ UL,
                                             const int* __restrict__ nU_p,
                                             float* __restrict__ out) {
    int nU = nU_p[0];
    if (nU == 0) return;
    int wid  = threadIdx.x >> 6;
    int lane = threadIdx.x & 63;
    for (int u = blockIdx.x * 4 + wid; u < nU; u += gridDim.x * 4) {
        int i = UL[u];
        const int* arow = adj + (size_t)i * N_ROWS;
        float m2 = -INFINITY;
        for (int j0 = lane * 4; j0 < N_ROWS; j0 += 256) {
            int4   a  = *(const int4*)(arow + j0);
            float4 sx = *(const float4*)(s_g + j0);
            if (a.x > 0) m2 = fmaxf(m2, sx.x);
            if (a.y > 0) m2 = fmaxf(m2, sx.y);
            if (a.z > 0) m2 = fmaxf(m2, sx.z);
            if (a.w > 0) m2 = fmaxf(m2, sx.w);
        }
#pragma unroll
        for (int off = 32; off > 0; off >>= 1)
            m2 = fmaxf(m2, __shfl_down(m2, off, 64));
        m2 = __shfl(m2, 0, 64);

        if (m2 > -INFINITY) {
            // streaming exact accumulate; p underflows to 0 like reference
            float acc0 = 0.f, acc1 = 0.f, den = 0.f;
            for (int j = 0; j < N_ROWS; ++j) {
                if (arow[j] > 0) {
                    float p = __expf(s_g[j] - m2);
                    if (p > 0.f) {
                        den += p;
                        const float* hr = h + (size_t)j * NIN;
                        float d0 = 0.f, d1 = 0.f;
                        for (int nn = 0; nn < NIN; ++nn) {
                            float hv = hr[nn];
                            d0 = fmaf(hv, w[(size_t)nn * NOUT + lane], d0);
                            d1 = fmaf(hv, w[(size_t)nn * NOUT + 64 + lane], d1);
                        }
                        acc0 = fmaf(p, d0, acc0);
                        acc1 = fmaf(p, d1, acc1);
                    }
                }
            }
            out[(size_t)i * NOUT + lane]      = acc0 / den;
            out[(size_t)i * NOUT + 64 + lane] = acc1 / den;
        } else {
            // fully-masked row: uniform softmax -> colsum(h) @ w / N
            float cs[4] = {0.f, 0.f, 0.f, 0.f};
            for (int r = 0; r < N_ROWS; ++r) {
                const float* hr = h + (size_t)r * NIN;
#pragma unroll
                for (int q = 0; q < 4; ++q)
                    cs[q] += hr[lane + q * 64];
            }
            float acc0 = 0.f, acc1 = 0.f;
            for (int nn = 0; nn < NIN; ++nn) {
                float csv = __shfl(cs[nn >> 6], nn & 63, 64);
                acc0 = fmaf(csv, w[(size_t)nn * NOUT + lane], acc0);
                acc1 = fmaf(csv, w[(size_t)nn * NOUT + 64 + lane], acc1);
            }
            out[(size_t)i * NOUT + lane]      = acc0 / (float)N_ROWS;
            out[(size_t)i * NOUT + 64 + lane] = acc1 / (float)N_ROWS;
        }
    }
}

// ---------------------------------------------------------------------------
extern "C" void kernel_launch(void* const* d_in, const int* in_sizes, int n_in,
                              void* d_out, int out_size, void* d_ws, size_t ws_size,
                              hipStream_t stream) {
    const float* h   = (const float*)d_in[0];   // [8192, 256]
    const int*   adj = (const int*)  d_in[1];   // [8192, 8192]
    const float* w   = (const float*)d_in[2];   // [256, 128]
    const float* v   = (const float*)d_in[3];   // [256, 1]
    float* out = (float*)d_out;                 // [8192, 128]

    // workspace layout (bytes)
    char* ws = (char*)d_ws;
    float* hwL = (float*)(ws);                                  // 128 KiB
    size_t o   = (size_t)MAXL * NOUT * 4;
    float* s   = (float*)(ws + o);  o += (size_t)N_ROWS * 4;    // 32 KiB
    int*   L   = (int*)  (ws + o);  o += (size_t)N_ROWS * 4;    // 32 KiB
    float* Ls  = (float*)(ws + o);  o += (size_t)N_ROWS * 4;    // 32 KiB
    int*   UL  = (int*)  (ws + o);  o += (size_t)N_ROWS * 4;    // 32 KiB
    int*   nL  = (int*)  (ws + o);  o += 16;
    float* T   = (float*)(ws + o);  o += 16;
    int*   nU  = (int*)  (ws + o);

    k_sw  <<<N_ROWS / 8, 256, 0, stream>>>(h, w, v, s);
    k_top <<<1,          256, 0, stream>>>(s, L, Ls, nL, T, nU);
    k_hwL <<<128,        128, 0, stream>>>(h, w, L, nL, hwL);
    k_att7<<<N_ROWS / 4, 256, 0, stream>>>(adj, hwL, L, Ls, nL, T, out, UL, nU);
    k_fix <<<2048,       256, 0, stream>>>(adj, s, h, w, UL, nU, out);
}